// Round 6
// baseline (107.157 us; speedup 1.0000x reference)
//
#include <hip/hip_runtime.h>
#include <hip/hip_bf16.h>

// SimCLR NT-Xent loss. B=4096, D=256, N=2B=8192 rows.
// loss = (1/N) sum_i [ log(denom_i) - log(pos_i) ]
//
// R18: R17's no-LDS triangular 64x64 wave-tile structure, register-
// disciplined. R17 counters (denom 41.9us, VGPR=96, FETCH 8.2MB, MFMA 7%,
// occupancy 16%) showed the compiler did NOT keep the 128 VGPRs of MFMA
// fragments resident: it sank/rematerialized the global loads into the
// MFMA loop (+ scratch traffic), exposing ~200cy L2 latency per step with
// ~1.3 waves/SIMD of TLP. Fixes:
//  - B streamed one 16-row block per nt iteration (bf = 16 regs, not 64)
//  - A fragments pinned resident via empty asm "+v" (no remat/sink)
//  - __launch_bounds__(256, 4): 128-VGPR cap, 4 waves/SIMD guaranteed
//  - col-partials reduced+stored per-nt (scalar cs, frees 4 regs)
// Everything else identical to R17 (passed): bijective 129x64 triangular
// decode over 128 strips, direct-L2 32B-contiguous fragment loads, exp,
// single-writer stores to P[128][128][64] f32 (4MB, no init, no atomics).

#define NROWS 8192
#define BHALF 4096
#define DDIM  256

typedef __attribute__((ext_vector_type(4))) int   i32x4;
typedef __attribute__((ext_vector_type(8))) int   i32x8;
typedef __attribute__((ext_vector_type(4))) float f32x4;

#define SCALE1 0x7F7F7F7F               // e8m0 biased-127 = 2^0 in every byte
#define TWO_LOG2E 2.8853900817779268f   // 2/ln(2): exp(2x) = exp2(x*TWO_LOG2E)

// Kernel 1: norms + fp8-normalized matrix + positive-pair log partials +
// out zero-init. (unchanged, verified)
__global__ __launch_bounds__(256) void prep_kernel(const float* __restrict__ z1,
                                                   const float* __restrict__ z2,
                                                   unsigned char* __restrict__ zn8,
                                                   float* __restrict__ posPart,
                                                   float* __restrict__ out) {
    __shared__ float sp[4];
    int wave = threadIdx.x >> 6;
    int lane = threadIdx.x & 63;
    int i    = blockIdx.x * 4 + wave;
    float4 a = reinterpret_cast<const float4*>(z1 + (size_t)i * DDIM)[lane];
    float4 b = reinterpret_cast<const float4*>(z2 + (size_t)i * DDIM)[lane];
    float ss1 = a.x * a.x + a.y * a.y + a.z * a.z + a.w * a.w;
    float ss2 = b.x * b.x + b.y * b.y + b.z * b.z + b.w * b.w;
    float dd  = a.x * b.x + a.y * b.y + a.z * b.z + a.w * b.w;
    #pragma unroll
    for (int off = 32; off; off >>= 1) {
        ss1 += __shfl_xor(ss1, off);
        ss2 += __shfl_xor(ss2, off);
        dd  += __shfl_xor(dd, off);
    }
    float n1 = fmaxf(sqrtf(ss1), 1e-8f);
    float n2 = fmaxf(sqrtf(ss2), 1e-8f);
    float i1 = 1.0f / n1, i2 = 1.0f / n2;
    int pa = __builtin_amdgcn_cvt_pk_fp8_f32(a.x * i1, a.y * i1, 0, 0);
    pa     = __builtin_amdgcn_cvt_pk_fp8_f32(a.z * i1, a.w * i1, pa, 1);
    int pb = __builtin_amdgcn_cvt_pk_fp8_f32(b.x * i2, b.y * i2, 0, 0);
    pb     = __builtin_amdgcn_cvt_pk_fp8_f32(b.z * i2, b.w * i2, pb, 1);
    reinterpret_cast<int*>(zn8 + (size_t)i * DDIM)[lane] = pa;
    reinterpret_cast<int*>(zn8 + (size_t)(i + BHALF) * DDIM)[lane] = pb;
    if (lane == 0) sp[wave] = __logf(dd * i1 * i2);
    if (blockIdx.x == 0 && threadIdx.x == 64) out[0] = 0.0f;
    __syncthreads();
    if (threadIdx.x == 0)
        posPart[blockIdx.x] = sp[0] + sp[1] + sp[2] + sp[3];
}

// Kernel 2: no-LDS wave-independent 64x64 tiles, A resident / B streamed.
__global__ __launch_bounds__(256, 4) void denom_kernel(const unsigned char* __restrict__ zn8,
                                                       float* __restrict__ P) {
    int t    = threadIdx.x;
    int lane = t & 63;
    int col  = lane & 15;
    int quad = lane >> 4;

    // global wave id -> triangular (ti, tj), 0 <= ti <= tj < 128
    int w = blockIdx.x * 4 + (t >> 6);      // [0, 8256)
    int y = w / 129, x = w - y * 129;       // grid 129 x 64
    int ti, tj;
    if (x > y) { ti = y;       tj = x - 1;   }
    else       { ti = 127 - y; tj = 127 - x; }
    int iBase = ti * 64, jBase = tj * 64;
    bool isDiag = (ti == tj);

    // direct L2 fragment loads: lane holds rows (base + mt*16 + col),
    // k-bytes [ks*128 + quad*32, +32) — contiguous 32B in global memory.
    const unsigned char* aBase = zn8 + (size_t)(iBase + col) * DDIM + quad * 32;
    const unsigned char* bBase = zn8 + (size_t)(jBase + col) * DDIM + quad * 32;

    // ---- A fragments: load once, PIN resident (no remat/sink) ----
    i32x8 af[4][2];
    #pragma unroll
    for (int mt = 0; mt < 4; mt++)
        #pragma unroll
        for (int ks = 0; ks < 2; ks++)
            af[mt][ks] = *(const i32x8*)(aBase + mt * 16 * DDIM + ks * 128);
    #pragma unroll
    for (int mt = 0; mt < 4; mt++)
        #pragma unroll
        for (int ks = 0; ks < 2; ks++)
            asm volatile("" : "+v"(af[mt][ks]));   // rule-17 keep-alive pin

    float rs[4][4];                     // row-sums (C layout: row = quad*4+r)
    #pragma unroll
    for (int mt = 0; mt < 4; mt++)
        #pragma unroll
        for (int r = 0; r < 4; r++) rs[mt][r] = 0.f;

    // ---- stream B one 16-row block per nt ----
    #pragma unroll
    for (int nt = 0; nt < 4; nt++) {
        i32x8 b0 = *(const i32x8*)(bBase + nt * 16 * DDIM);
        i32x8 b1 = *(const i32x8*)(bBase + nt * 16 * DDIM + 128);

        float csn = 0.f;                // col-sum partial for this nt block
        #pragma unroll
        for (int mt = 0; mt < 4; mt++) {
            f32x4 acc = {0.f, 0.f, 0.f, 0.f};
            acc = __builtin_amdgcn_mfma_scale_f32_16x16x128_f8f6f4(
                      af[mt][0], b0, acc, 0, 0, 0, SCALE1, 0, SCALE1);
            acc = __builtin_amdgcn_mfma_scale_f32_16x16x128_f8f6f4(
                      af[mt][1], b1, acc, 0, 0, 0, SCALE1, 0, SCALE1);
            bool dtile = isDiag && (mt == nt);
            #pragma unroll
            for (int r = 0; r < 4; r++) {
                float e = exp2f(acc[r] * TWO_LOG2E);
                if (dtile && (quad * 4 + r) == col) e = 0.f;
                rs[mt][r] += e;
                csn       += e;
            }
        }

        // col partial: reduce over quads; store at transposed slot (tj, ti)
        if (!isDiag) {
            csn += __shfl_xor(csn, 16);
            csn += __shfl_xor(csn, 32);
            if (quad == 0)
                P[((size_t)tj * 128 + ti) * 64 + nt * 16 + col] = csn;
        }
    }

    // row partials: reduce over the 16 col-lanes within each quad
    #pragma unroll
    for (int mt = 0; mt < 4; mt++)
        #pragma unroll
        for (int r = 0; r < 4; r++) {
            float v = rs[mt][r];
            v += __shfl_xor(v, 1);
            v += __shfl_xor(v, 2);
            v += __shfl_xor(v, 4);
            v += __shfl_xor(v, 8);
            rs[mt][r] = v;
        }
    if (col == 0) {
        float* Prow = P + ((size_t)ti * 128 + tj) * 64;
        #pragma unroll
        for (int mt = 0; mt < 4; mt++) {
            f32x4 v4 = { rs[mt][0], rs[mt][1], rs[mt][2], rs[mt][3] };
            *reinterpret_cast<f32x4*>(Prow + mt * 16 + quad * 4) = v4;
        }
    }
}

// Kernel 3: per-row 128-slot reduction of P (coalesced, L2-resident) + final
// loss reduction, 32 blocks, atomic into prep-zeroed out[0].
__global__ __launch_bounds__(256) void loss_kernel(const float* __restrict__ posPart,
                                                   const float* __restrict__ P,
                                                   float* __restrict__ out) {
    __shared__ float sdata[4];
    int t = threadIdx.x;
    int i = blockIdx.x * 256 + t;
    int bi = i >> 6, r = i & 63;
    const float* p = P + ((size_t)bi << 13) + r;   // bi*128*64 + r
    float d0 = 0.f, d1 = 0.f, d2 = 0.f, d3 = 0.f;
    #pragma unroll
    for (int k = 0; k < 128; k += 4) {
        d0 += p[(k + 0) << 6];
        d1 += p[(k + 1) << 6];
        d2 += p[(k + 2) << 6];
        d3 += p[(k + 3) << 6];
    }
    float s = __logf((d0 + d1) + (d2 + d3));
    if (t < 32) s -= 2.0f * posPart[blockIdx.x * 32 + t];
    #pragma unroll
    for (int off = 32; off; off >>= 1) s += __shfl_xor(s, off);
    if ((t & 63) == 0) sdata[t >> 6] = s;
    __syncthreads();
    if (t == 0)
        atomicAdd(out, (sdata[0] + sdata[1] + sdata[2] + sdata[3]) * (1.0f / NROWS));
}

extern "C" void kernel_launch(void* const* d_in, const int* in_sizes, int n_in,
                              void* d_out, int out_size, void* d_ws, size_t ws_size,
                              hipStream_t stream) {
    const float* z1 = (const float*)d_in[0];
    const float* z2 = (const float*)d_in[1];

    // ws: zn8 fp8 [8192*256] (2 MB) | P f32[128][128][64] (4 MB) | posPart f32[1024]
    unsigned char* zn8 = (unsigned char*)d_ws;
    float* P       = (float*)((char*)d_ws + (size_t)NROWS * DDIM);
    float* posPart = P + (size_t)128 * 128 * 64;

    prep_kernel<<<BHALF / 4, 256, 0, stream>>>(z1, z2, zn8, posPart, (float*)d_out);
    denom_kernel<<<2064, 256, 0, stream>>>(zn8, P);
    loss_kernel<<<NROWS / 256, 256, 0, stream>>>(posPart, P, (float*)d_out);
}

// Round 7
// 93.468 us; speedup vs baseline: 1.1465x; 1.1465x over previous
//
#include <hip/hip_runtime.h>
#include <hip/hip_bf16.h>

// SimCLR NT-Xent loss. B=4096, D=256, N=2B=8192 rows.
// loss = (1/N) sum_i [ log(denom_i) - log(pos_i) ]
//
// R19 = R13 (best verified: 86.59us total, denom ~25-27us inferred) with
// three surgical deltas, everything else byte-identical:
//  (i)  A-fragments direct L2->regs (R17-verified 32B-contiguous pattern),
//       issued alongside the B0 stage so latency hides under one wait
//  (ii) LDS 48->32KB (two clean B buffers) -> 4 blocks/CU expected
//       (VGPR ~120 natural; launch_bounds(256,3) is a no-spill floor,
//       R18 lesson: tight bound + pins => 64-VGPR spill disaster)
//  (iii) B-frags streamed per-nt (16 regs) + per-wave-partial P stores
//       (R16-verified P[64][64][2][128] single-writer scheme) -> all tail
//       parking barriers deleted; 2 __syncthreads per block (vs 4-5)
// Model being tested: denom rides the poison-fill's ~40us L2-writeback
// storm; LDS-staged wide loads are storm-resistant, extra TLP rides it
// better. If total pins ~82-86 with healthy counters, the storm floor
// (fill 41.5 + ~40 shadow) is the structural limit.

#define NROWS 8192
#define BHALF 4096
#define DDIM  256

typedef __attribute__((ext_vector_type(4))) int   i32x4;
typedef __attribute__((ext_vector_type(8))) int   i32x8;
typedef __attribute__((ext_vector_type(4))) float f32x4;

#define SCALE1 0x7F7F7F7F               // e8m0 biased-127 = 2^0 in every byte
#define TWO_LOG2E 2.8853900817779268f   // 2/ln(2): exp(2x) = exp2(x*TWO_LOG2E)

__device__ __forceinline__ void load_lds16(const unsigned char* g, unsigned char* l) {
    __builtin_amdgcn_global_load_lds(
        (const __attribute__((address_space(1))) void*)g,
        (__attribute__((address_space(3))) void*)l, 16, 0, 0);
}

// Kernel 1: norms + fp8-normalized matrix + positive-pair log partials +
// out zero-init. (unchanged, verified)
__global__ __launch_bounds__(256) void prep_kernel(const float* __restrict__ z1,
                                                   const float* __restrict__ z2,
                                                   unsigned char* __restrict__ zn8,
                                                   float* __restrict__ posPart,
                                                   float* __restrict__ out) {
    __shared__ float sp[4];
    int wave = threadIdx.x >> 6;
    int lane = threadIdx.x & 63;
    int i    = blockIdx.x * 4 + wave;
    float4 a = reinterpret_cast<const float4*>(z1 + (size_t)i * DDIM)[lane];
    float4 b = reinterpret_cast<const float4*>(z2 + (size_t)i * DDIM)[lane];
    float ss1 = a.x * a.x + a.y * a.y + a.z * a.z + a.w * a.w;
    float ss2 = b.x * b.x + b.y * b.y + b.z * b.z + b.w * b.w;
    float dd  = a.x * b.x + a.y * b.y + a.z * b.z + a.w * b.w;
    #pragma unroll
    for (int off = 32; off; off >>= 1) {
        ss1 += __shfl_xor(ss1, off);
        ss2 += __shfl_xor(ss2, off);
        dd  += __shfl_xor(dd, off);
    }
    float n1 = fmaxf(sqrtf(ss1), 1e-8f);
    float n2 = fmaxf(sqrtf(ss2), 1e-8f);
    float i1 = 1.0f / n1, i2 = 1.0f / n2;
    int pa = __builtin_amdgcn_cvt_pk_fp8_f32(a.x * i1, a.y * i1, 0, 0);
    pa     = __builtin_amdgcn_cvt_pk_fp8_f32(a.z * i1, a.w * i1, pa, 1);
    int pb = __builtin_amdgcn_cvt_pk_fp8_f32(b.x * i2, b.y * i2, 0, 0);
    pb     = __builtin_amdgcn_cvt_pk_fp8_f32(b.z * i2, b.w * i2, pb, 1);
    reinterpret_cast<int*>(zn8 + (size_t)i * DDIM)[lane] = pa;
    reinterpret_cast<int*>(zn8 + (size_t)(i + BHALF) * DDIM)[lane] = pb;
    if (lane == 0) sp[wave] = __logf(dd * i1 * i2);
    if (blockIdx.x == 0 && threadIdx.x == 64) out[0] = 0.0f;
    __syncthreads();
    if (threadIdx.x == 0)
        posPart[blockIdx.x] = sp[0] + sp[1] + sp[2] + sp[3];
}

// Kernel 2: triangular 128x128 tiles (R13 schedule); A direct from L2,
// B double-buffered in 32KB LDS; per-wave-partial single-writer P stores.
__global__ __launch_bounds__(256, 3) void denom_kernel(const unsigned char* __restrict__ zn8,
                                                       float* __restrict__ P) {
    __shared__ __align__(16) unsigned char sMem[32 * 1024];
    unsigned char* buf0 = sMem;
    unsigned char* buf1 = sMem + 16384;

    // triangular decode: 65x32 grid -> {(bi,bj) : 0 <= bi <= bj < 64}
    int x = blockIdx.x, y = blockIdx.y;
    int bi, bj;
    if (x > y) { bi = y;      bj = x - 1;  }
    else       { bi = 63 - y; bj = 63 - x; }
    int iBase = bi * 128;
    int jBase = bj * 128;
    bool isDiag = (bi == bj);

    int t    = threadIdx.x;
    int lane = t & 63;
    int wave = t >> 6;
    int col  = lane & 15;
    int quad = lane >> 4;
    int wm = wave >> 1, wn = wave & 1;

    // staging addresses (row = q*16 + rowL at slab q*4096 + rowL*256;
    // 16B slot (t&15) holds k-chunk (t&15)^rowL — R13-verified XOR swizzle)
    int rowL  = t >> 4;
    int chunk = (t & 15) ^ rowL;

    // ---- stage B half 0 into buf0 ----
    {
        const unsigned char* gB = zn8 + (size_t)(jBase + rowL) * DDIM + chunk * 16;
        #pragma unroll
        for (int q = 0; q < 4; q++)
            load_lds16(gB + q * 4096, buf0 + t * 16 + q * 4096);
    }

    // ---- A fragments direct from L2 (R17-verified 32B-contiguous loads);
    //      latency hides under the B0 stage wait ----
    const unsigned char* aBase = zn8 + (size_t)(iBase + wm * 64 + col) * DDIM + quad * 32;
    i32x8 af[4][2];
    #pragma unroll
    for (int mt = 0; mt < 4; mt++)
        #pragma unroll
        for (int ks = 0; ks < 2; ks++)
            af[mt][ks] = *(const i32x8*)(aBase + mt * 16 * DDIM + ks * 128);
    __builtin_amdgcn_sched_barrier(0);   // don't sink the A loads below here
    __syncthreads();                     // drains B0 DMA + A arrivals

    // ---- stage B half 1 into buf1 (flies during half-0 compute) ----
    {
        const unsigned char* gB = zn8 + (size_t)(jBase + 64 + rowL) * DDIM + chunk * 16;
        #pragma unroll
        for (int q = 0; q < 4; q++)
            load_lds16(gB + q * 4096, buf1 + t * 16 + q * 4096);
    }

    float rs[4][4];                     // row-sums over both halves
    #pragma unroll
    for (int mt = 0; mt < 4; mt++)
        #pragma unroll
        for (int r = 0; r < 4; r++) rs[mt][r] = 0.f;

    #pragma unroll
    for (int h = 0; h < 2; h++) {
        if (h) __syncthreads();          // drains B1 (issued one phase ago)
        const unsigned char* bRow =
            (h ? buf1 : buf0) + (size_t)(wn * 32 + col) * DDIM;

        // stream B fragments one 16-row block per nt (16 regs live)
        #pragma unroll
        for (int nt = 0; nt < 2; nt++) {
            i32x8 bfr[2];
            #pragma unroll
            for (int ks = 0; ks < 2; ks++) {
                int g0 = ks * 8 + quad * 2;
                i32x4 lo = *(const i32x4*)(bRow + nt * 16 * DDIM + ((g0    ) ^ col) * 16);
                i32x4 hi = *(const i32x4*)(bRow + nt * 16 * DDIM + ((g0 + 1) ^ col) * 16);
                bfr[ks] = __builtin_shufflevector(lo, hi, 0, 1, 2, 3, 4, 5, 6, 7);
            }

            float csn = 0.f;
            #pragma unroll
            for (int mt = 0; mt < 4; mt++) {
                int gi = iBase + wm * 64 + mt * 16;
                f32x4 acc = {0.f, 0.f, 0.f, 0.f};
                acc = __builtin_amdgcn_mfma_scale_f32_16x16x128_f8f6f4(
                          af[mt][0], bfr[0], acc, 0, 0, 0, SCALE1, 0, SCALE1);
                acc = __builtin_amdgcn_mfma_scale_f32_16x16x128_f8f6f4(
                          af[mt][1], bfr[1], acc, 0, 0, 0, SCALE1, 0, SCALE1);
                bool dtile = (gi == jBase + h * 64 + wn * 32 + nt * 16);
                #pragma unroll
                for (int r = 0; r < 4; r++) {
                    float e = exp2f(acc[r] * TWO_LOG2E);
                    if (dtile && (quad * 4 + r) == col) e = 0.f;
                    rs[mt][r] += e;
                    csn       += e;
                }
            }

            // col partial for cols jBase+h*64+wn*32+nt*16+[0,16): reduce over
            // quads, store per-wm partial at slot (bj, bi, s=wm). Single-writer.
            if (!isDiag) {
                csn += __shfl_xor(csn, 16);
                csn += __shfl_xor(csn, 32);
                if (quad == 0)
                    P[(((size_t)bj * 64 + bi) * 2 + wm) * 128
                      + h * 64 + wn * 32 + nt * 16 + col] = csn;
            }
        }
    }

    // ---- row partials: reduce 16 col-lanes, store per-wn partial at slot
    //      (bi, bj, s=wn). Pure register path — no barriers needed. ----
    #pragma unroll
    for (int mt = 0; mt < 4; mt++)
        #pragma unroll
        for (int r = 0; r < 4; r++) {
            float v = rs[mt][r];
            v += __shfl_xor(v, 1);
            v += __shfl_xor(v, 2);
            v += __shfl_xor(v, 4);
            v += __shfl_xor(v, 8);
            rs[mt][r] = v;
        }
    if (col == 0) {
        float* Pr = P + (((size_t)bi * 64 + bj) * 2 + wn) * 128;
        #pragma unroll
        for (int mt = 0; mt < 4; mt++) {
            f32x4 v4 = { rs[mt][0], rs[mt][1], rs[mt][2], rs[mt][3] };
            *reinterpret_cast<f32x4*>(Pr + wm * 64 + mt * 16 + quad * 4) = v4;
        }
    }
}

// Kernel 3: per-row 128-slot reduction of P (coalesced, L2-resident) + final
// loss reduction, 32 blocks, atomic into prep-zeroed out[0]. (R16-verified)
__global__ __launch_bounds__(256) void loss_kernel(const float* __restrict__ posPart,
                                                   const float* __restrict__ P,
                                                   float* __restrict__ out) {
    __shared__ float sdata[4];
    int t = threadIdx.x;
    int i = blockIdx.x * 256 + t;
    int bi = i >> 7, r = i & 127;
    const float* p = P + ((size_t)bi << 14) + r;   // bi*64*2*128 + r
    float d0 = 0.f, d1 = 0.f, d2 = 0.f, d3 = 0.f;
    #pragma unroll
    for (int k = 0; k < 128; k += 4) {
        d0 += p[(k + 0) << 7];
        d1 += p[(k + 1) << 7];
        d2 += p[(k + 2) << 7];
        d3 += p[(k + 3) << 7];
    }
    float s = __logf((d0 + d1) + (d2 + d3));
    if (t < 32) s -= 2.0f * posPart[blockIdx.x * 32 + t];
    #pragma unroll
    for (int off = 32; off; off >>= 1) s += __shfl_xor(s, off);
    if ((t & 63) == 0) sdata[t >> 6] = s;
    __syncthreads();
    if (t == 0)
        atomicAdd(out, (sdata[0] + sdata[1] + sdata[2] + sdata[3]) * (1.0f / NROWS));
}

extern "C" void kernel_launch(void* const* d_in, const int* in_sizes, int n_in,
                              void* d_out, int out_size, void* d_ws, size_t ws_size,
                              hipStream_t stream) {
    const float* z1 = (const float*)d_in[0];
    const float* z2 = (const float*)d_in[1];

    // ws: zn8 fp8 [8192*256] (2 MB) | P f32[64][64][2][128] (4 MB) | posPart f32[1024]
    unsigned char* zn8 = (unsigned char*)d_ws;
    float* P       = (float*)((char*)d_ws + (size_t)NROWS * DDIM);
    float* posPart = P + (size_t)64 * 64 * 2 * 128;

    prep_kernel<<<BHALF / 4, 256, 0, stream>>>(z1, z2, zn8, posPart, (float*)d_out);
    denom_kernel<<<dim3(65, 32), 256, 0, stream>>>(zn8, P);
    loss_kernel<<<NROWS / 256, 256, 0, stream>>>(posPart, P, (float*)d_out);
}

// Round 8
// 86.307 us; speedup vs baseline: 1.2416x; 1.0830x over previous
//
#include <hip/hip_runtime.h>
#include <hip/hip_bf16.h>

// SimCLR NT-Xent loss. B=4096, D=256, N=2B=8192 rows.
// loss = (1/N) sum_i [ log(denom_i) - log(pos_i) ]
//
// R20 = R13 structure (best verified 86.59us) with ONE lever: denom LDS
// 48KB -> 32KB to raise occupancy 3 -> 4 blocks/CU (+33% TLP).
// R19 lesson reverted: A stays DMA-staged via global_load_lds (storm-
// resistant); its direct-L2 variant cost +7us. Plan:
//   phase1: DMA A-half0->buf0, A-half1->buf1 (wave-pair wm reads only its
//           own 64 rows); barrier
//   phase2: A-frags -> regs (R13-verified XOR-swizzle reads); barrier
//           (drains lgkm -> buffers safely reusable)
//   phase3: DMA B0->buf0, B1->buf1; barrier; compute h0,h1 back-to-back
// Outputs: R16/R19-verified per-wave-partial single-writer stores to
// P[64][64][2][128] f32 (4MB, no init, no atomics) -> zero tail barriers.
// launch_bounds(256,3) = no-spill floor (R18 lesson: never force a cap);
// natural VGPR ~100-110 < 128 gives 4 waves/SIMD -> 4 blocks/CU.

#define NROWS 8192
#define BHALF 4096
#define DDIM  256

typedef __attribute__((ext_vector_type(4))) int   i32x4;
typedef __attribute__((ext_vector_type(8))) int   i32x8;
typedef __attribute__((ext_vector_type(4))) float f32x4;

#define SCALE1 0x7F7F7F7F               // e8m0 biased-127 = 2^0 in every byte
#define TWO_LOG2E 2.8853900817779268f   // 2/ln(2): exp(2x) = exp2(x*TWO_LOG2E)

__device__ __forceinline__ void load_lds16(const unsigned char* g, unsigned char* l) {
    __builtin_amdgcn_global_load_lds(
        (const __attribute__((address_space(1))) void*)g,
        (__attribute__((address_space(3))) void*)l, 16, 0, 0);
}

// Kernel 1: norms + fp8-normalized matrix + positive-pair log partials +
// out zero-init. (unchanged, verified)
__global__ __launch_bounds__(256) void prep_kernel(const float* __restrict__ z1,
                                                   const float* __restrict__ z2,
                                                   unsigned char* __restrict__ zn8,
                                                   float* __restrict__ posPart,
                                                   float* __restrict__ out) {
    __shared__ float sp[4];
    int wave = threadIdx.x >> 6;
    int lane = threadIdx.x & 63;
    int i    = blockIdx.x * 4 + wave;
    float4 a = reinterpret_cast<const float4*>(z1 + (size_t)i * DDIM)[lane];
    float4 b = reinterpret_cast<const float4*>(z2 + (size_t)i * DDIM)[lane];
    float ss1 = a.x * a.x + a.y * a.y + a.z * a.z + a.w * a.w;
    float ss2 = b.x * b.x + b.y * b.y + b.z * b.z + b.w * b.w;
    float dd  = a.x * b.x + a.y * b.y + a.z * b.z + a.w * b.w;
    #pragma unroll
    for (int off = 32; off; off >>= 1) {
        ss1 += __shfl_xor(ss1, off);
        ss2 += __shfl_xor(ss2, off);
        dd  += __shfl_xor(dd, off);
    }
    float n1 = fmaxf(sqrtf(ss1), 1e-8f);
    float n2 = fmaxf(sqrtf(ss2), 1e-8f);
    float i1 = 1.0f / n1, i2 = 1.0f / n2;
    int pa = __builtin_amdgcn_cvt_pk_fp8_f32(a.x * i1, a.y * i1, 0, 0);
    pa     = __builtin_amdgcn_cvt_pk_fp8_f32(a.z * i1, a.w * i1, pa, 1);
    int pb = __builtin_amdgcn_cvt_pk_fp8_f32(b.x * i2, b.y * i2, 0, 0);
    pb     = __builtin_amdgcn_cvt_pk_fp8_f32(b.z * i2, b.w * i2, pb, 1);
    reinterpret_cast<int*>(zn8 + (size_t)i * DDIM)[lane] = pa;
    reinterpret_cast<int*>(zn8 + (size_t)(i + BHALF) * DDIM)[lane] = pb;
    if (lane == 0) sp[wave] = __logf(dd * i1 * i2);
    if (blockIdx.x == 0 && threadIdx.x == 64) out[0] = 0.0f;
    __syncthreads();
    if (threadIdx.x == 0)
        posPart[blockIdx.x] = sp[0] + sp[1] + sp[2] + sp[3];
}

// Kernel 2: triangular 128x128 tiles, 32KB LDS, A DMA-staged per wave-pair.
__global__ __launch_bounds__(256, 3) void denom_kernel(const unsigned char* __restrict__ zn8,
                                                       float* __restrict__ P) {
    __shared__ __align__(16) unsigned char sMem[32 * 1024];
    unsigned char* buf0 = sMem;
    unsigned char* buf1 = sMem + 16384;

    // triangular decode: 65x32 grid -> {(bi,bj) : 0 <= bi <= bj < 64}
    int x = blockIdx.x, y = blockIdx.y;
    int bi, bj;
    if (x > y) { bi = y;      bj = x - 1;  }
    else       { bi = 63 - y; bj = 63 - x; }
    int iBase = bi * 128;
    int jBase = bj * 128;
    bool isDiag = (bi == bj);

    int t    = threadIdx.x;
    int lane = t & 63;
    int wave = t >> 6;
    int col  = lane & 15;
    int quad = lane >> 4;
    int wm = wave >> 1, wn = wave & 1;

    // staging: 64-row half -> 16KB buffer; row (q*16 + rowL) at slab
    // q*4096 + rowL*256; 16B slot (t&15) holds k-chunk (t&15)^rowL
    // (R13-verified XOR swizzle, matched on read by ^col since col==row%16)
    int rowL  = t >> 4;
    int chunk = (t & 15) ^ rowL;

    // ---- phase 1: DMA A-half0 -> buf0, A-half1 -> buf1 ----
    {
        const unsigned char* gA = zn8 + (size_t)(iBase + rowL) * DDIM + chunk * 16;
        #pragma unroll
        for (int q = 0; q < 4; q++)
            load_lds16(gA + q * 4096, buf0 + t * 16 + q * 4096);
        #pragma unroll
        for (int q = 0; q < 4; q++)
            load_lds16(gA + 16384 + q * 4096, buf1 + t * 16 + q * 4096);
    }
    __syncthreads();                    // A DMA landed

    // ---- phase 2: A-fragments -> registers (wave-pair reads own half) ----
    i32x8 af[4][2];
    {
        const unsigned char* aRow = (wm ? buf1 : buf0) + (size_t)col * DDIM;
        #pragma unroll
        for (int mt = 0; mt < 4; mt++)
            #pragma unroll
            for (int ks = 0; ks < 2; ks++) {
                int g0 = ks * 8 + quad * 2;
                i32x4 lo = *(const i32x4*)(aRow + mt * 16 * DDIM + ((g0    ) ^ col) * 16);
                i32x4 hi = *(const i32x4*)(aRow + mt * 16 * DDIM + ((g0 + 1) ^ col) * 16);
                af[mt][ks] = __builtin_shufflevector(lo, hi, 0, 1, 2, 3, 4, 5, 6, 7);
            }
    }
    __syncthreads();                    // all A reads done -> buffers reusable

    // ---- phase 3: DMA B0 -> buf0, B1 -> buf1; one drain; compute both ----
    {
        const unsigned char* gB = zn8 + (size_t)(jBase + rowL) * DDIM + chunk * 16;
        #pragma unroll
        for (int q = 0; q < 4; q++)
            load_lds16(gB + q * 4096, buf0 + t * 16 + q * 4096);
        #pragma unroll
        for (int q = 0; q < 4; q++)
            load_lds16(gB + 16384 + q * 4096, buf1 + t * 16 + q * 4096);
    }
    __syncthreads();                    // B DMA landed; no more barriers

    float rs[4][4];                     // row-sums over both halves
    #pragma unroll
    for (int mt = 0; mt < 4; mt++)
        #pragma unroll
        for (int r = 0; r < 4; r++) rs[mt][r] = 0.f;

    #pragma unroll
    for (int h = 0; h < 2; h++) {
        const unsigned char* bRow =
            (h ? buf1 : buf0) + (size_t)(wn * 32 + col) * DDIM;

        // stream B fragments one 16-row block per nt (16 regs live)
        #pragma unroll
        for (int nt = 0; nt < 2; nt++) {
            i32x8 bfr[2];
            #pragma unroll
            for (int ks = 0; ks < 2; ks++) {
                int g0 = ks * 8 + quad * 2;
                i32x4 lo = *(const i32x4*)(bRow + nt * 16 * DDIM + ((g0    ) ^ col) * 16);
                i32x4 hi = *(const i32x4*)(bRow + nt * 16 * DDIM + ((g0 + 1) ^ col) * 16);
                bfr[ks] = __builtin_shufflevector(lo, hi, 0, 1, 2, 3, 4, 5, 6, 7);
            }

            float csn = 0.f;
            #pragma unroll
            for (int mt = 0; mt < 4; mt++) {
                int gi = iBase + wm * 64 + mt * 16;
                f32x4 acc = {0.f, 0.f, 0.f, 0.f};
                acc = __builtin_amdgcn_mfma_scale_f32_16x16x128_f8f6f4(
                          af[mt][0], bfr[0], acc, 0, 0, 0, SCALE1, 0, SCALE1);
                acc = __builtin_amdgcn_mfma_scale_f32_16x16x128_f8f6f4(
                          af[mt][1], bfr[1], acc, 0, 0, 0, SCALE1, 0, SCALE1);
                bool dtile = (gi == jBase + h * 64 + wn * 32 + nt * 16);
                #pragma unroll
                for (int r = 0; r < 4; r++) {
                    float e = exp2f(acc[r] * TWO_LOG2E);
                    if (dtile && (quad * 4 + r) == col) e = 0.f;
                    rs[mt][r] += e;
                    csn       += e;
                }
            }

            // col partial: reduce over quads, store per-wm partial at slot
            // (bj, bi, s=wm). Single-writer, no atomics.
            if (!isDiag) {
                csn += __shfl_xor(csn, 16);
                csn += __shfl_xor(csn, 32);
                if (quad == 0)
                    P[(((size_t)bj * 64 + bi) * 2 + wm) * 128
                      + h * 64 + wn * 32 + nt * 16 + col] = csn;
            }
        }
    }

    // ---- row partials: reduce 16 col-lanes, store per-wn partial at slot
    //      (bi, bj, s=wn). Pure register path — no barriers. ----
    #pragma unroll
    for (int mt = 0; mt < 4; mt++)
        #pragma unroll
        for (int r = 0; r < 4; r++) {
            float v = rs[mt][r];
            v += __shfl_xor(v, 1);
            v += __shfl_xor(v, 2);
            v += __shfl_xor(v, 4);
            v += __shfl_xor(v, 8);
            rs[mt][r] = v;
        }
    if (col == 0) {
        float* Pr = P + (((size_t)bi * 64 + bj) * 2 + wn) * 128;
        #pragma unroll
        for (int mt = 0; mt < 4; mt++) {
            f32x4 v4 = { rs[mt][0], rs[mt][1], rs[mt][2], rs[mt][3] };
            *reinterpret_cast<f32x4*>(Pr + wm * 64 + mt * 16 + quad * 4) = v4;
        }
    }
}

// Kernel 3: per-row 128-slot reduction of P (coalesced, L2-resident) + final
// loss reduction, 32 blocks, atomic into prep-zeroed out[0]. (R19-verified)
__global__ __launch_bounds__(256) void loss_kernel(const float* __restrict__ posPart,
                                                   const float* __restrict__ P,
                                                   float* __restrict__ out) {
    __shared__ float sdata[4];
    int t = threadIdx.x;
    int i = blockIdx.x * 256 + t;
    int bi = i >> 7, r = i & 127;
    const float* p = P + ((size_t)bi << 14) + r;   // bi*64*2*128 + r
    float d0 = 0.f, d1 = 0.f, d2 = 0.f, d3 = 0.f;
    #pragma unroll
    for (int k = 0; k < 128; k += 4) {
        d0 += p[(k + 0) << 7];
        d1 += p[(k + 1) << 7];
        d2 += p[(k + 2) << 7];
        d3 += p[(k + 3) << 7];
    }
    float s = __logf((d0 + d1) + (d2 + d3));
    if (t < 32) s -= 2.0f * posPart[blockIdx.x * 32 + t];
    #pragma unroll
    for (int off = 32; off; off >>= 1) s += __shfl_xor(s, off);
    if ((t & 63) == 0) sdata[t >> 6] = s;
    __syncthreads();
    if (t == 0)
        atomicAdd(out, (sdata[0] + sdata[1] + sdata[2] + sdata[3]) * (1.0f / NROWS));
}

extern "C" void kernel_launch(void* const* d_in, const int* in_sizes, int n_in,
                              void* d_out, int out_size, void* d_ws, size_t ws_size,
                              hipStream_t stream) {
    const float* z1 = (const float*)d_in[0];
    const float* z2 = (const float*)d_in[1];

    // ws: zn8 fp8 [8192*256] (2 MB) | P f32[64][64][2][128] (4 MB) | posPart f32[1024]
    unsigned char* zn8 = (unsigned char*)d_ws;
    float* P       = (float*)((char*)d_ws + (size_t)NROWS * DDIM);
    float* posPart = P + (size_t)64 * 64 * 2 * 128;

    prep_kernel<<<BHALF / 4, 256, 0, stream>>>(z1, z2, zn8, posPart, (float*)d_out);
    denom_kernel<<<dim3(65, 32), 256, 0, stream>>>(zn8, P);
    loss_kernel<<<NROWS / 256, 256, 0, stream>>>(posPart, P, (float*)d_out);
}